// Round 10
// baseline (3110.065 us; speedup 1.0000x reference)
//
#include <hip/hip_runtime.h>
#include <stdint.h>

#define NROWS 65536
#define HD 1024

typedef __attribute__((ext_vector_type(8))) short bf16x8;   // 8 bf16 in 4 VGPRs
typedef __attribute__((ext_vector_type(16))) float f32x16;  // MFMA 32x32 accumulator

typedef __attribute__((address_space(1))) const unsigned int* gas_ptr;
typedef __attribute__((address_space(3))) unsigned int* las_ptr;

__device__ __forceinline__ unsigned short f2bf(float f) {
  union { float f; uint32_t u; } v; v.f = f;
  uint32_t u = v.u;
  return (unsigned short)((u + 0x7fffu + ((u >> 16) & 1u)) >> 16);  // RNE
}

__device__ __forceinline__ void gl16(const void* g, void* l) {
  __builtin_amdgcn_global_load_lds((gas_ptr)g, (las_ptr)l, 16, 0, 0);
}

// ---------------- prep: W2 fp32 -> bf16, swizzled granules (R5 layout) ----------------
// W2bf[c][k]; 16B granule g stored at (g&~3) | ((g&3) ^ ((c>>1)&3)).
__global__ void k_w2bf(const float* __restrict__ W2, unsigned short* __restrict__ W2bf) {
  int i = blockIdx.x * 256 + threadIdx.x;   // 131072 threads, 1 granule each
  int c = i >> 7, g = i & 127;
  const float4* s4 = (const float4*)(W2 + (size_t)c * HD + g * 8);
  float4 a = s4[0], b = s4[1];
  uint4 pk;
  pk.x = (uint32_t)f2bf(a.x) | ((uint32_t)f2bf(a.y) << 16);
  pk.y = (uint32_t)f2bf(a.z) | ((uint32_t)f2bf(a.w) << 16);
  pk.z = (uint32_t)f2bf(b.x) | ((uint32_t)f2bf(b.y) << 16);
  pk.w = (uint32_t)f2bf(b.z) | ((uint32_t)f2bf(b.w) << 16);
  int gs = (g & 124) | ((g & 3) ^ ((c >> 1) & 3));
  *(uint4*)(W2bf + (size_t)c * HD + gs * 8) = pk;
}

// ---------------- layer 1 (R5): h bf16 [65536][1024], granule swizzle (g&3)^((row>>1)&3) ----------------
__global__ __launch_bounds__(512) void k_layer1(
    const float* __restrict__ x, const float* __restrict__ W1,
    const float* __restrict__ b1, const float* __restrict__ Wmeta,
    const float* __restrict__ bmeta, unsigned short* __restrict__ h) {
  __shared__ float xs[128 * 12];
  int r0 = blockIdx.x * 128;
  int t = threadIdx.x;
  int j0 = t * 2;
  float w1a = W1[j0], w1b = W1[j0 + 1];
  float b1a = b1[j0], b1b = b1[j0 + 1];
  float wma[10], wmb[10], bma[10], bmb[10];
#pragma unroll
  for (int e = 0; e < 10; e++) {
    float2 wmv = *(const float2*)(Wmeta + e * HD + j0);
    float2 bmv = *(const float2*)(bmeta + e * HD + j0);
    wma[e] = wmv.x; wmb[e] = wmv.y; bma[e] = bmv.x; bmb[e] = bmv.y;
  }
  for (int i = t; i < 128 * 12; i += 512) xs[i] = x[(size_t)r0 * 12 + i];
  __syncthreads();
  int g = j0 >> 3;
  for (int r = 0; r < 128; r++) {
    const float* xr = xs + r * 12;
    float delta = xr[10], phi = xr[11];
    float s1a = 0.f, s1b = 0.f, s2a = 0.f, s2b = 0.f;
#pragma unroll
    for (int e = 0; e < 10; e++) {
      float oh = xr[e];
      s1a = fmaf(oh, wma[e], s1a);
      s1b = fmaf(oh, wmb[e], s1b);
      s2a = fmaf(oh, bma[e], s2a);
      s2b = fmaf(oh, bmb[e], s2b);
    }
    float pa = fmaf(delta, w1a, b1a) + fmaf(phi, s1a, s2a);
    float pb = fmaf(delta, w1b, b1b) + fmaf(phi, s1b, s2b);
    pa = fmaxf(pa, 0.f); pb = fmaxf(pb, 0.f);
    uint32_t pk = (uint32_t)f2bf(pa) | ((uint32_t)f2bf(pb) << 16);
    int rr = r0 + r;
    int gs = (g & 124) | ((g & 3) ^ ((rr >> 1) & 3));
    *(uint32_t*)(h + (size_t)rr * HD + gs * 8 + (j0 & 7)) = pk;
  }
}

// ---------------- layers 2+3: R5 structure at BK=32, 8 blocks/CU (full 32 waves/CU) ----------------
// grid 4096 (XCD-swizzled) = 512 rt x 8 ct; 256 threads = 4 waves (2x2), wave tile 64x64
// = 2x2 of 32x32x16 bf16 MFMA (acc 64 AGPR). BK=32, 32 K-tiles.
// Per tile: {4 gl_lds (A 8KB + B 8KB) | __syncthreads | 8 ds_read_b128 + 8 MFMA | __syncthreads}.
// LDS = 16896 B (16384 staging; epilogue needs 16896) -> 8 blocks/CU; the per-tile
// vmcnt drain is hidden by 8 resident blocks' mutual overlap (TLP, not ILP).
__global__ __launch_bounds__(256, 8) void k_gemm(
    const unsigned short* __restrict__ h, const unsigned short* __restrict__ W2bf,
    const float* __restrict__ b2, const float* __restrict__ W3,
    float* __restrict__ partial) {
  __shared__ char lds[16896];   // A @0 (8KB), B @8192 (8KB); epilogue float2[64*33]
  int tid = threadIdx.x;
  // XCD swizzle: 4096 blocks = 8 XCDs x 512; XCD k gets contiguous logical range.
  int b = (int)blockIdx.x;
  int bx = ((b & 7) << 9) | (b >> 3);
  int rt = bx >> 3, ct = bx & 7;   // 8 consecutive bx share rt -> A-panel L2 reuse
  size_t r0 = (size_t)rt * 128;
  int c0 = ct * 128;
  int w = tid >> 6, lane = tid & 63;
  int wm = w >> 1, wn = w & 1;
  int l31 = lane & 31, hi = lane >> 5;
  int sw = (l31 >> 1) & 3;   // granule swizzle key (row bases are multiples of 32)

  f32x16 acc[2][2];
#pragma unroll
  for (int rb = 0; rb < 2; rb++)
#pragma unroll
    for (int cb = 0; cb < 2; cb++)
#pragma unroll
      for (int i = 0; i < 16; i++) acc[rb][cb][i] = 0.f;

  int arow = (wm * 64 + l31) * 64;   // + rb*2048 (32 rows)
  int brow = (wn * 64 + l31) * 64;   // + cb*2048

  for (int T = 0; T < 32; T++) {
    // stage tile T: A rows r0..+127 k T*32..+31 -> lds[0..8K), B -> lds[8K..16K)
#pragma unroll
    for (int q = 0; q < 2; q++) {
      int s = tid + 256 * q;            // 0..511
      int row = s >> 2, g4 = s & 3;
      gl16(h    + (r0 + row) * (size_t)HD + T * 32 + g4 * 8, lds +        (size_t)s * 16);
      gl16(W2bf + (size_t)(c0 + row) * HD + T * 32 + g4 * 8, lds + 8192 + (size_t)s * 16);
    }
    __syncthreads();   // drains vmcnt: tile T landed; prior reads done before overwrite
#pragma unroll
    for (int kl = 0; kl < 2; kl++) {
      int slot = ((kl * 2 + hi) ^ sw) << 4;
      bf16x8 a0 = *(const bf16x8*)(lds + arow + slot);
      bf16x8 a1 = *(const bf16x8*)(lds + arow + 2048 + slot);
      bf16x8 b0 = *(const bf16x8*)(lds + 8192 + brow + slot);
      bf16x8 b1 = *(const bf16x8*)(lds + 8192 + brow + 2048 + slot);
      acc[0][0] = __builtin_amdgcn_mfma_f32_32x32x16_bf16(a0, b0, acc[0][0], 0, 0, 0);
      acc[0][1] = __builtin_amdgcn_mfma_f32_32x32x16_bf16(a0, b1, acc[0][1], 0, 0, 0);
      acc[1][0] = __builtin_amdgcn_mfma_f32_32x32x16_bf16(a1, b0, acc[1][0], 0, 0, 0);
      acc[1][1] = __builtin_amdgcn_mfma_f32_32x32x16_bf16(a1, b1, acc[1][1], 0, 0, 0);
    }
    __syncthreads();
  }

  // ---- epilogue: v = relu(acc+b2); o = v x W3^T; 4 transpose-reduce passes (rb x wm-half) ----
  float b2c[2], w30[2], w31[2];
#pragma unroll
  for (int cb = 0; cb < 2; cb++) {
    int c = c0 + wn * 64 + cb * 32 + l31;
    b2c[cb] = b2[c];
    w30[cb] = W3[c];
    w31[cb] = W3[HD + c];
  }
  float2* sE = (float2*)lds;   // 64 lines x 33 float2 = 16896 B
#pragma unroll
  for (int rb = 0; rb < 2; rb++) {
#pragma unroll
    for (int wmp = 0; wmp < 2; wmp++) {
      __syncthreads();
      if (wm == wmp) {
#pragma unroll
        for (int reg = 0; reg < 16; reg++) {
          float v0 = fmaxf(acc[rb][0][reg] + b2c[0], 0.f);
          float v1 = fmaxf(acc[rb][1][reg] + b2c[1], 0.f);
          float2 o;
          o.x = v0 * w30[0] + v1 * w30[1];
          o.y = v0 * w31[0] + v1 * w31[1];
          int rowf = (reg & 3) + 8 * (reg >> 2) + 4 * hi;   // verified C/D row map
          int line = rowf * 2 + wn;                          // [0,64)
          sE[line * 33 + l31] = o;
        }
      }
      __syncthreads();
      // reduce: 64 targets (rowf 32 x d 2), 4 threads each summing 16 of 64 col-partials
      int tgt = tid >> 2, sub = tid & 3;
      int rowf_t = tgt >> 1, d = tgt & 1;
      float s = 0.f;
#pragma unroll
      for (int j = 0; j < 16; j++) {
        int jj = sub * 16 + j;                 // 0..63
        float2 v = sE[(rowf_t * 2 + (jj >> 5)) * 33 + (jj & 31)];
        s += d ? v.y : v.x;
      }
      s += __shfl_xor(s, 1);
      s += __shfl_xor(s, 2);
      if (sub == 0) {
        int row = wmp * 64 + rb * 32 + rowf_t;
        partial[(size_t)ct * (NROWS * 2) + (r0 + row) * 2 + d] = s;
      }
    }
  }
}

// ---------------- final: out = b3 + sum over 8 col-tile partials ----------------
__global__ void k_reduce(const float* __restrict__ partial, const float* __restrict__ b3,
                         float* __restrict__ out) {
  int i = blockIdx.x * 256 + threadIdx.x;  // 131072
  float s = b3[i & 1];
#pragma unroll
  for (int ctt = 0; ctt < 8; ctt++) s += partial[(size_t)ctt * 131072 + i];
  out[i] = s;
}

extern "C" void kernel_launch(void* const* d_in, const int* in_sizes, int n_in,
                              void* d_out, int out_size, void* d_ws, size_t ws_size,
                              hipStream_t stream) {
  const float* x     = (const float*)d_in[0];
  const float* W1    = (const float*)d_in[1];
  const float* b1    = (const float*)d_in[2];
  const float* Wmeta = (const float*)d_in[3];
  const float* bmeta = (const float*)d_in[4];
  const float* W2    = (const float*)d_in[5];
  const float* b2    = (const float*)d_in[6];
  const float* W3    = (const float*)d_in[7];
  const float* b3    = (const float*)d_in[8];
  float* out = (float*)d_out;

  char* ws = (char*)d_ws;
  unsigned short* hbuf  = (unsigned short*)ws;                              // 128 MiB
  unsigned short* W2bf  = (unsigned short*)(ws + (size_t)NROWS * HD * 2);   // 2 MiB
  float* partial = (float*)(ws + (size_t)NROWS * HD * 2 + (size_t)HD * HD * 2);  // 4 MiB (8 slices)

  k_w2bf<<<512, 256, 0, stream>>>(W2, W2bf);
  k_layer1<<<512, 512, 0, stream>>>(x, W1, b1, Wmeta, bmeta, hbuf);
  k_gemm<<<4096, 256, 0, stream>>>(hbuf, W2bf, b2, W3, partial);
  k_reduce<<<512, 256, 0, stream>>>(partial, b3, out);
}

// Round 11
// 209.115 us; speedup vs baseline: 14.8725x; 14.8725x over previous
//
#include <hip/hip_runtime.h>
#include <stdint.h>

#define NROWS 65536
#define HD 1024

typedef __attribute__((ext_vector_type(8))) short bf16x8;  // 8 bf16 in 4 VGPRs
typedef __attribute__((ext_vector_type(4))) float f32x4;   // MFMA 16x16 accumulator

typedef __attribute__((address_space(1))) const unsigned int* gas_ptr;
typedef __attribute__((address_space(3))) unsigned int* las_ptr;

__device__ __forceinline__ unsigned short f2bf(float f) {
  union { float f; uint32_t u; } v; v.f = f;
  uint32_t u = v.u;
  return (unsigned short)((u + 0x7fffu + ((u >> 16) & 1u)) >> 16);  // RNE
}

__device__ __forceinline__ void gl16(const void* g, void* l) {
  __builtin_amdgcn_global_load_lds((gas_ptr)g, (las_ptr)l, 16, 0, 0);
}

// ---------------- prep: W2 fp32 -> bf16, granule swizzle (g&3)^(c&3) [R7-verified] ----------------
__global__ void k_w2bf(const float* __restrict__ W2, unsigned short* __restrict__ W2bf) {
  int i = blockIdx.x * 256 + threadIdx.x;   // 131072 threads, 1 granule each
  int c = i >> 7, g = i & 127;
  const float4* s4 = (const float4*)(W2 + (size_t)c * HD + g * 8);
  float4 a = s4[0], b = s4[1];
  uint4 pk;
  pk.x = (uint32_t)f2bf(a.x) | ((uint32_t)f2bf(a.y) << 16);
  pk.y = (uint32_t)f2bf(a.z) | ((uint32_t)f2bf(a.w) << 16);
  pk.z = (uint32_t)f2bf(b.x) | ((uint32_t)f2bf(b.y) << 16);
  pk.w = (uint32_t)f2bf(b.z) | ((uint32_t)f2bf(b.w) << 16);
  int gs = (g & 124) | ((g & 3) ^ (c & 3));
  *(uint4*)(W2bf + (size_t)c * HD + gs * 8) = pk;
}

// ---------------- layer 1: h bf16 [65536][1024], granule swizzle (g&3)^(row&3) [R7-verified] ----------------
__global__ __launch_bounds__(512) void k_layer1(
    const float* __restrict__ x, const float* __restrict__ W1,
    const float* __restrict__ b1, const float* __restrict__ Wmeta,
    const float* __restrict__ bmeta, unsigned short* __restrict__ h) {
  __shared__ float xs[128 * 12];
  int r0 = blockIdx.x * 128;
  int t = threadIdx.x;
  int j0 = t * 2;
  float w1a = W1[j0], w1b = W1[j0 + 1];
  float b1a = b1[j0], b1b = b1[j0 + 1];
  float wma[10], wmb[10], bma[10], bmb[10];
#pragma unroll
  for (int e = 0; e < 10; e++) {
    float2 wmv = *(const float2*)(Wmeta + e * HD + j0);
    float2 bmv = *(const float2*)(bmeta + e * HD + j0);
    wma[e] = wmv.x; wmb[e] = wmv.y; bma[e] = bmv.x; bmb[e] = bmv.y;
  }
  for (int i = t; i < 128 * 12; i += 512) xs[i] = x[(size_t)r0 * 12 + i];
  __syncthreads();
  int g = j0 >> 3;
  for (int r = 0; r < 128; r++) {
    const float* xr = xs + r * 12;
    float delta = xr[10], phi = xr[11];
    float s1a = 0.f, s1b = 0.f, s2a = 0.f, s2b = 0.f;
#pragma unroll
    for (int e = 0; e < 10; e++) {
      float oh = xr[e];
      s1a = fmaf(oh, wma[e], s1a);
      s1b = fmaf(oh, wmb[e], s1b);
      s2a = fmaf(oh, bma[e], s2a);
      s2b = fmaf(oh, bmb[e], s2b);
    }
    float pa = fmaf(delta, w1a, b1a) + fmaf(phi, s1a, s2a);
    float pb = fmaf(delta, w1b, b1b) + fmaf(phi, s1b, s2b);
    pa = fmaxf(pa, 0.f); pb = fmaxf(pb, 0.f);
    uint32_t pk = (uint32_t)f2bf(pa) | ((uint32_t)f2bf(pb) << 16);
    int rr = r0 + r;
    int gs = (g & 124) | ((g & 3) ^ (rr & 3));
    *(uint32_t*)(h + (size_t)rr * HD + gs * 8 + (j0 & 7)) = pk;
  }
}

// ---------------- layers 2+3: m201-geometry 256x256 tile, 4-phase K-sliced pipeline ----------------
// grid 1024 (XCD-swizzled) = 256 rt x 4 ct; 512 threads = 8 waves (2wm x 4wn),
// wave tile 128x64 = 8x4 frags of 16x16x32 bf16 MFMA (acc 128 VGPR).
// LDS: 2 buffers x (A[256][64] 32KB + B[256][64] 32KB) = 128 KiB. BK=64, 16 K-tiles.
// Per K-tile, 4 phases (mh,ks) = (0,0),(1,0),(0,1),(1,1); each:
//   {ds_read A-frags(4) [+B-frags(4) if mh==0] | 2 gl_lds: one K-slice half of tile
//    T+1 -> other buffer | barrier | lgkmcnt(0)+sched_barrier | setprio(1) 16 MFMA
//    setprio(0) | [vmcnt(4) after (1,0) and (1,1)] | barrier}.
// vmcnt(4) leaves only the newest K-slice-half (4 loads) in flight; guarantees the
// slice needed by the NEXT two phases has landed. Never drains to 0 until tile 15.
__global__ __launch_bounds__(512) void k_gemm(
    const unsigned short* __restrict__ h, const unsigned short* __restrict__ W2bf,
    const float* __restrict__ b2, const float* __restrict__ W3,
    float* __restrict__ partial) {
  extern __shared__ char lds[];
  int tid = threadIdx.x;
  // XCD swizzle: 1024 blocks = 8 XCDs x 128; 4 consecutive bx share rt (A-panel L2 reuse).
  int b = (int)blockIdx.x;
  int bx = ((b & 7) << 7) | (b >> 3);
  int rt = bx >> 2, ct = bx & 3;
  size_t r0 = (size_t)rt * 256;
  int c0 = ct * 256;
  int w = tid >> 6, lane = tid & 63;
  int wm = w >> 2, wn = w & 3;
  int l15 = lane & 15, l4 = lane >> 4;
  int gsw = (l4 ^ (l15 & 3)) << 4;                 // swizzled granule byte (per-thread const)
  int aBase = (wm * 128 + l15) * 64 + gsw;         // + mh*4096 + Mf*1024 + ks*16384 + buf
  int bBase = 32768 + (wn * 64 + l15) * 64 + gsw;  // + Nf*1024 + ks*16384 + buf

  f32x4 acc[8][4];
#pragma unroll
  for (int fm = 0; fm < 8; fm++)
#pragma unroll
    for (int fn = 0; fn < 4; fn++)
#pragma unroll
      for (int i = 0; i < 4; i++) acc[fm][fn][i] = 0.f;

  // staging bases: thread handles granule idx=tid (rows 0..127) and idx=tid+512 (rows 128..255)
  const unsigned short* srcA0 = h    + (r0 + (tid >> 2)) * (size_t)HD + (tid & 3) * 8;
  const unsigned short* srcB0 = W2bf + (size_t)(c0 + (tid >> 2)) * HD + (tid & 3) * 8;
  const unsigned short* srcA1 = srcA0 + 128 * (size_t)HD;
  const unsigned short* srcB1 = srcB0 + 128 * (size_t)HD;

  // stage one K-slice half (ks) of tile T's A or B into buffer (T&1): 2 gl_lds
#define STAGE_A(T, ks)                                                              \
  do {                                                                              \
    char* dst = lds + ((T) & 1) * 65536 + (ks) * 16384 + (size_t)tid * 16;          \
    gl16(srcA0 + (T) * 64 + (ks) * 32, dst);                                        \
    gl16(srcA1 + (T) * 64 + (ks) * 32, dst + 8192);                                 \
  } while (0)
#define STAGE_B(T, ks)                                                              \
  do {                                                                              \
    char* dst = lds + ((T) & 1) * 65536 + 32768 + (ks) * 16384 + (size_t)tid * 16;  \
    gl16(srcB0 + (T) * 64 + (ks) * 32, dst);                                        \
    gl16(srcB1 + (T) * 64 + (ks) * 32, dst + 8192);                                 \
  } while (0)

#define MFMA16(MH)                                                                          \
  do {                                                                                      \
    __builtin_amdgcn_s_setprio(1);                                                          \
    _Pragma("unroll")                                                                       \
    for (int i = 0; i < 4; i++)                                                             \
      _Pragma("unroll")                                                                     \
      for (int j = 0; j < 4; j++)                                                           \
        acc[(MH)*4 + i][j] =                                                                \
            __builtin_amdgcn_mfma_f32_16x16x32_bf16(Af[i], Bf[j], acc[(MH)*4 + i][j], 0, 0, 0); \
    __builtin_amdgcn_s_setprio(0);                                                          \
  } while (0)

  // prologue: stage tile 0 fully (8 loads); ks0 landed (newest 4 = ks1 may fly); barrier.
  STAGE_A(0, 0); STAGE_B(0, 0); STAGE_A(0, 1); STAGE_B(0, 1);
  asm volatile("s_waitcnt vmcnt(4)" ::: "memory");
  __builtin_amdgcn_s_barrier();

#pragma unroll 2
  for (int T = 0; T < 16; T++) {
    int base = (T & 1) * 65536;
    bf16x8 Af[4], Bf[4];
    // ---- phase (0,0): A[mh0,ks0] + B[ks0] reads; stage T+1 A-ks0 ----
#pragma unroll
    for (int i = 0; i < 4; i++) {
      Af[i] = *(const bf16x8*)(lds + base + aBase + i * 1024);
      Bf[i] = *(const bf16x8*)(lds + base + bBase + i * 1024);
    }
    if (T < 15) STAGE_A(T + 1, 0);
    __builtin_amdgcn_s_barrier();
    asm volatile("s_waitcnt lgkmcnt(0)" ::: "memory");
    __builtin_amdgcn_sched_barrier(0);
    MFMA16(0);
    __builtin_amdgcn_s_barrier();
    // ---- phase (1,0): A[mh1,ks0] reads (B reused); stage T+1 B-ks0; vmcnt guards own ks1 ----
#pragma unroll
    for (int i = 0; i < 4; i++)
      Af[i] = *(const bf16x8*)(lds + base + aBase + 4096 + i * 1024);
    if (T < 15) STAGE_B(T + 1, 0);
    __builtin_amdgcn_s_barrier();
    asm volatile("s_waitcnt lgkmcnt(0)" ::: "memory");
    __builtin_amdgcn_sched_barrier(0);
    MFMA16(1);
    if (T == 15) { asm volatile("s_waitcnt vmcnt(0)" ::: "memory"); }
    else         { asm volatile("s_waitcnt vmcnt(4)" ::: "memory"); }
    __builtin_amdgcn_s_barrier();
    // ---- phase (0,1): A[mh0,ks1] + B[ks1] reads; stage T+1 A-ks1 ----
#pragma unroll
    for (int i = 0; i < 4; i++) {
      Af[i] = *(const bf16x8*)(lds + base + aBase + 16384 + i * 1024);
      Bf[i] = *(const bf16x8*)(lds + base + bBase + 16384 + i * 1024);
    }
    if (T < 15) STAGE_A(T + 1, 1);
    __builtin_amdgcn_s_barrier();
    asm volatile("s_waitcnt lgkmcnt(0)" ::: "memory");
    __builtin_amdgcn_sched_barrier(0);
    MFMA16(0);
    __builtin_amdgcn_s_barrier();
    // ---- phase (1,1): A[mh1,ks1] reads; stage T+1 B-ks1; vmcnt guards next tile's ks0 ----
#pragma unroll
    for (int i = 0; i < 4; i++)
      Af[i] = *(const bf16x8*)(lds + base + aBase + 4096 + 16384 + i * 1024);
    if (T < 15) STAGE_B(T + 1, 1);
    __builtin_amdgcn_s_barrier();
    asm volatile("s_waitcnt lgkmcnt(0)" ::: "memory");
    __builtin_amdgcn_sched_barrier(0);
    MFMA16(1);
    if (T < 15) { asm volatile("s_waitcnt vmcnt(4)" ::: "memory"); }
    __builtin_amdgcn_s_barrier();
  }
  __syncthreads();

  // ---- epilogue: v = relu(acc+b2); o = v x W3^T; 16-lane shfl reduce; cross-wn via LDS ----
  float b2c[4], w30[4], w31[4];
#pragma unroll
  for (int fn = 0; fn < 4; fn++) {
    int c = c0 + wn * 64 + fn * 16 + l15;
    b2c[fn] = b2[c];
    w30[fn] = W3[c];
    w31[fn] = W3[HD + c];
  }
  float* sOut = (float*)lds;  // [4 wn][256 rows][2] = 8 KB
#pragma unroll
  for (int fm = 0; fm < 8; fm++) {
#pragma unroll
    for (int reg = 0; reg < 4; reg++) {
      float o0 = 0.f, o1 = 0.f;
#pragma unroll
      for (int fn = 0; fn < 4; fn++) {
        float v = fmaxf(acc[fm][fn][reg] + b2c[fn], 0.f);
        o0 = fmaf(v, w30[fn], o0);
        o1 = fmaf(v, w31[fn], o1);
      }
#pragma unroll
      for (int m = 1; m <= 8; m <<= 1) {  // reduce over l15 (16 cols)
        o0 += __shfl_xor(o0, m);
        o1 += __shfl_xor(o1, m);
      }
      if (l15 == 0) {
        int row = wm * 128 + fm * 16 + l4 * 4 + reg;  // C/D row map (m89, R7-verified)
        sOut[(wn * 256 + row) * 2 + 0] = o0;
        sOut[(wn * 256 + row) * 2 + 1] = o1;
      }
    }
  }
  __syncthreads();
  {
    int j = tid;  // 512 values = 256 rows x 2 outputs
    float s = sOut[j] + sOut[512 + j] + sOut[1024 + j] + sOut[1536 + j];
    partial[(size_t)ct * (NROWS * 2) + r0 * 2 + j] = s;
  }
}

// ---------------- final: out = b3 + sum over 4 col-tile partials ----------------
__global__ void k_reduce(const float* __restrict__ partial, const float* __restrict__ b3,
                         float* __restrict__ out) {
  int i = blockIdx.x * 256 + threadIdx.x;  // 131072
  float s = b3[i & 1];
#pragma unroll
  for (int ctt = 0; ctt < 4; ctt++) s += partial[(size_t)ctt * 131072 + i];
  out[i] = s;
}

extern "C" void kernel_launch(void* const* d_in, const int* in_sizes, int n_in,
                              void* d_out, int out_size, void* d_ws, size_t ws_size,
                              hipStream_t stream) {
  const float* x     = (const float*)d_in[0];
  const float* W1    = (const float*)d_in[1];
  const float* b1    = (const float*)d_in[2];
  const float* Wmeta = (const float*)d_in[3];
  const float* bmeta = (const float*)d_in[4];
  const float* W2    = (const float*)d_in[5];
  const float* b2    = (const float*)d_in[6];
  const float* W3    = (const float*)d_in[7];
  const float* b3    = (const float*)d_in[8];
  float* out = (float*)d_out;

  char* ws = (char*)d_ws;
  unsigned short* hbuf  = (unsigned short*)ws;                              // 128 MiB
  unsigned short* W2bf  = (unsigned short*)(ws + (size_t)NROWS * HD * 2);   // 2 MiB
  float* partial = (float*)(ws + (size_t)NROWS * HD * 2 + (size_t)HD * HD * 2);  // 2 MiB (4 slices)

  hipFuncSetAttribute((const void*)k_gemm, hipFuncAttributeMaxDynamicSharedMemorySize, 131072);

  k_w2bf<<<512, 256, 0, stream>>>(W2, W2bf);
  k_layer1<<<512, 512, 0, stream>>>(x, W1, b1, Wmeta, bmeta, hbuf);
  k_gemm<<<1024, 512, 131072, stream>>>(hbuf, W2bf, b2, W3, partial);
  k_reduce<<<512, 256, 0, stream>>>(partial, b3, out);
}